// Round 1
// 242.860 us; speedup vs baseline: 1.0127x; 1.0127x over previous
//
#include <hip/hip_runtime.h>

#define NN 8192     // nodes
#define NB 32       // graphs
#define NG 256      // nodes per graph
#define NE 65536    // edges per graph type
#define DK 512
#define HC 32
#define DB 2048     // body visual dim
#define DF 512      // face visual dim

#define BODY_DW (NN*DB/4)            // 4194304 dwords of fp8x4 (body)
#define FACE_DW (NN*DF/4)            // 1048576 dwords of fp8x4 (face)
#define B_BODY (BODY_DW/2048)        // 2048 pack blocks, 8 out-dwords/thread
#define B_FACE (FACE_DW/2048)        // 512 pack blocks
#define B_CNT  512                   // degree-count blocks

typedef float v2f __attribute__((ext_vector_type(2)));

#if __has_builtin(__builtin_amdgcn_cvt_pk_f32_fp8) && __has_builtin(__builtin_amdgcn_cvt_pk_fp8_f32)
#define HW_FP8 1
#else
#define HW_FP8 0
#endif

// ---- fp8 e4m3fn helpers (manual fallback only if builtins missing) ----
__device__ __forceinline__ float fp8_dec(unsigned u) {
    unsigned e = (u >> 3) & 15u, m = u & 7u, s = u & 0x80u;
    float v = e ? __uint_as_float(((e + 120u) << 23) | (m << 20))
                : (float)m * 0.001953125f;
    return s ? -v : v;
}
__device__ __forceinline__ unsigned fp8_enc(float x) {
    unsigned sb = (__float_as_uint(x) >> 24) & 0x80u;
    float a = fabsf(x);
    if (a >= 448.f) return sb | 0x7Eu;
    if (a < 0.015625f) {
        int c = (int)rintf(a * 512.f);
        if (c > 7) return sb | 0x08u;
        return sb | (unsigned)c;
    }
    int ex; (void)frexpf(a, &ex);
    float p = ldexpf(a, 1 - ex);
    int m = (int)rintf((p - 1.f) * 8.f);
    int e = ex - 1 + 7;
    if (m == 8) { m = 0; e++; }
    if (e >= 16) return sb | 0x7Eu;
    return sb | (unsigned)(e << 3) | (unsigned)m;
}
__device__ __forceinline__ unsigned pack4_fp8(float x, float y, float z, float w) {
#if HW_FP8
    int u = __builtin_amdgcn_cvt_pk_fp8_f32(x, y, 0, false);
    u = __builtin_amdgcn_cvt_pk_fp8_f32(z, w, u, true);
    return (unsigned)u;
#else
    return fp8_enc(x) | (fp8_enc(y) << 8) | (fp8_enc(z) << 16) | (fp8_enc(w) << 24);
#endif
}
__device__ __forceinline__ float fp8dot4(unsigned a, unsigned b) {
#if HW_FP8
    v2f al = __builtin_amdgcn_cvt_pk_f32_fp8((int)a, false);
    v2f ah = __builtin_amdgcn_cvt_pk_f32_fp8((int)a, true);
    v2f bl = __builtin_amdgcn_cvt_pk_f32_fp8((int)b, false);
    v2f bh = __builtin_amdgcn_cvt_pk_f32_fp8((int)b, true);
    return al.x*bl.x + al.y*bl.y + ah.x*bh.x + ah.y*bh.y;
#else
    float s = 0.f;
    #pragma unroll
    for (int j = 0; j < 4; j++)
        s += fp8_dec((a >> (8*j)) & 255u) * fp8_dec((b >> (8*j)) & 255u);
    return s;
#endif
}
__device__ __forceinline__ float fp8dot16(int4 a, int4 b) {
    return fp8dot4((unsigned)a.x, (unsigned)b.x) + fp8dot4((unsigned)a.y, (unsigned)b.y)
         + fp8dot4((unsigned)a.z, (unsigned)b.z) + fp8dot4((unsigned)a.w, (unsigned)b.w);
}

struct Params {
    const float *vb, *vf, *x, *Wq, *Wk, *Wv, *ln_g, *ln_b, *prelu_a;
    const float *mlp_W, *mlp_b, *np_W, *np_b, *body_W, *body_b, *face_W, *face_b;
    const float *pb_W, *pb_b, *pf_W, *pf_b;
    const int *eib, *eif;
    unsigned *vnb, *vnf;
    float *invb, *invf;
    float *a_ws, *sb, *sf, *fused;   // fused[0..31]=body_W@pb_W, [32..63]=face_W@pf_W, [64]=cb, [65]=cf
    int *counts, *starts, *cursor, *esrc;
    float *out;
};

// ===== K1: fp8 pack (branch-free, 8x16B in flight) + degree count + attention + fused weight vecs =====
// blocks [0, B_BODY)                     : body pack
// blocks [B_BODY, B_BODY+B_FACE)         : face pack
// blocks [+B_CNT)                        : degree count
// blocks [+NB)                           : rank-2 attention
// last block                             : bw/fw/cb/cf precompute
__global__ __launch_bounds__(256) void k1_kernel(Params p) {
    __shared__ float2 xs[NG];
    __shared__ float pm[4][4];
    __shared__ float sm4[4];
    const int bid = blockIdx.x, tid = threadIdx.x;
    const int lane = tid & 63, wave = tid >> 6;

    if (bid < B_BODY + B_FACE) {
        const bool body = bid < B_BODY;
        const float4* src = body ? (const float4*)p.vb : (const float4*)p.vf;
        unsigned* dst = body ? p.vnb : p.vnf;
        const int base = (body ? bid : bid - B_BODY) * 2048 + tid;
        float4 v[8];
        #pragma unroll
        for (int j = 0; j < 8; j++) v[j] = src[base + j*256];      // all 8 loads issued up front
        #pragma unroll
        for (int j = 0; j < 8; j++)
            dst[base + j*256] = pack4_fp8(v[j].x, v[j].y, v[j].z, v[j].w);
        return;
    }
    if (bid < B_BODY + B_FACE + B_CNT) {
        const int e = (bid - B_BODY - B_FACE) * 256 + tid;
        if (e < NE) atomicAdd(&p.counts[p.eib[NE + e]], 1);
        else        atomicAdd(&p.counts[NN + p.eif[e]], 1);        // eif[NE + (e-NE)] == eif[e]
        return;
    }
    if (bid < B_BODY + B_FACE + B_CNT + NB) {
        const int gg = bid - (B_BODY + B_FACE + B_CNT);
        xs[tid] = ((const float2*)p.x)[gg*NG + tid];
        const int d = tid * 2;
        float q0a = p.Wq[d],    q0b = p.Wq[d+1];
        float q1a = p.Wq[DK+d], q1b = p.Wq[DK+d+1];
        float k0a = p.Wk[d],    k0b = p.Wk[d+1];
        float k1a = p.Wk[DK+d], k1b = p.Wk[DK+d+1];
        float m00 = q0a*k0a + q0b*k0b;
        float m01 = q0a*k1a + q0b*k1b;
        float m10 = q1a*k0a + q1b*k0b;
        float m11 = q1a*k1a + q1b*k1b;
        #pragma unroll
        for (int off = 32; off > 0; off >>= 1) {
            m00 += __shfl_down(m00,off); m01 += __shfl_down(m01,off);
            m10 += __shfl_down(m10,off); m11 += __shfl_down(m11,off);
        }
        if (lane == 0) { pm[wave][0]=m00; pm[wave][1]=m01; pm[wave][2]=m10; pm[wave][3]=m11; }
        __syncthreads();
        if (tid < 4) sm4[tid] = pm[0][tid] + pm[1][tid] + pm[2][tid] + pm[3][tid];
        __syncthreads();
        const float scale = 0.04419417382415922f;  // 1/sqrt(512)
        const float2 xi = xs[tid];
        const float u0 = (xi.x*sm4[0] + xi.y*sm4[2]) * scale;
        const float u1 = (xi.x*sm4[1] + xi.y*sm4[3]) * scale;
        float m = -1e30f;
        for (int j = 0; j < NG; j++) m = fmaxf(m, u0*xs[j].x + u1*xs[j].y);
        float S = 0.f, a0 = 0.f, a1 = 0.f;
        for (int j = 0; j < NG; j++) {
            float2 xj = xs[j];
            float pr = __expf(u0*xj.x + u1*xj.y - m);
            S += pr; a0 += pr*xj.x; a1 += pr*xj.y;
        }
        const float invS = 1.f / S;
        ((float2*)p.a_ws)[gg*NG + tid] = make_float2(a0*invS, a1*invS);
        return;
    }
    // fused projection vectors: bw[cp] = sum_c body_W[cp,c]*pb_W[c]  (and face analog)
    if (tid < HC) {
        float s = 0.f;
        #pragma unroll 8
        for (int c = 0; c < HC; c++) s += p.body_W[tid*HC + c] * p.pb_W[c];
        p.fused[tid] = s;
    } else if (tid < 2*HC) {
        const int cp = tid - HC;
        float s = 0.f;
        #pragma unroll 8
        for (int c = 0; c < HC; c++) s += p.face_W[cp*HC + c] * p.pf_W[c];
        p.fused[HC + cp] = s;
    } else if (tid == 2*HC) {
        float s = 0.f;
        for (int c = 0; c < HC; c++) s += p.body_b[c] * p.pb_W[c];
        p.fused[64] = s;
    } else if (tid == 2*HC + 1) {
        float s = 0.f;
        for (int c = 0; c < HC; c++) s += p.face_b[c] * p.pf_W[c];
        p.fused[65] = s;
    }
}

// ===== K2: CSR scan + node MLP pipeline (-> out base, sb, sf scalars) + invnorms =====
// blocks 0,1                         : exclusive scan
// blocks [2, 2+NN/4)                 : node pipeline (1 node / wave)
// blocks [2+NN/4, 2+NN/2)            : body invnorm
// blocks [2+NN/2, 2+3NN/4)           : face invnorm
__global__ __launch_bounds__(256) void k2_kernel(Params p) {
    __shared__ int part[256];
    __shared__ float t[4][DK];
    const int bid = blockIdx.x, tid = threadIdx.x;
    const int wave = tid >> 6, lane = tid & 63;
    const int B_NODE = NN/4;

    if (bid < 2) {
        const int cbase = bid * NN;
        const int sbase = bid * (NN + 1);
        int loc[32];
        int sum = 0;
        #pragma unroll
        for (int j = 0; j < 32; j++) { loc[j] = p.counts[cbase + tid*32 + j]; sum += loc[j]; }
        part[tid] = sum;
        __syncthreads();
        for (int off = 1; off < 256; off <<= 1) {
            int v = (tid >= off) ? part[tid - off] : 0;
            __syncthreads();
            part[tid] += v;
            __syncthreads();
        }
        int run = (tid == 0) ? 0 : part[tid - 1];
        #pragma unroll
        for (int j = 0; j < 32; j++) {
            p.starts[sbase + tid*32 + j] = run;
            p.cursor[cbase + tid*32 + j] = run;
            run += loc[j];
        }
        if (tid == 255) p.starts[sbase + NN] = run;
        return;
    }
    if (bid < 2 + B_NODE) {
        const int node = (bid - 2) * 4 + wave;
        const float a0 = p.a_ws[node*2], a1 = p.a_ws[node*2+1];
        const float4* wv0 = (const float4*)p.Wv;
        const float4* wv1 = (const float4*)(p.Wv + DK);
        const float4* g4 = (const float4*)p.ln_g;
        const float4* b4 = (const float4*)p.ln_b;
        float4 W0[2], W1[2], Gg[2], Bb[2];
        #pragma unroll
        for (int k = 0; k < 2; k++) {
            int c4 = lane*2 + k;
            W0[k] = wv0[c4]; W1[k] = wv1[c4]; Gg[k] = g4[c4]; Bb[k] = b4[c4];
        }
        float s0=0.f, s1=0.f, q00=0.f, q01=0.f, q11=0.f;
        #pragma unroll
        for (int k = 0; k < 2; k++) {
            const float* u = (const float*)&W0[k];
            const float* v = (const float*)&W1[k];
            #pragma unroll
            for (int j = 0; j < 4; j++) {
                s0 += u[j]; s1 += v[j];
                q00 += u[j]*u[j]; q01 += u[j]*v[j]; q11 += v[j]*v[j];
            }
        }
        #pragma unroll
        for (int off = 1; off < 64; off <<= 1) {
            s0 += __shfl_xor(s0,off); s1 += __shfl_xor(s1,off);
            q00 += __shfl_xor(q00,off); q01 += __shfl_xor(q01,off); q11 += __shfl_xor(q11,off);
        }
        const float mean = (a0*s0 + a1*s1) * (1.f/DK);
        const float msq  = (a0*a0*q00 + 2.f*a0*a1*q01 + a1*a1*q11) * (1.f/DK);
        const float inv  = rsqrtf(msq - mean*mean + 1e-5f);
        const float alpha = p.prelu_a[0];
        #pragma unroll
        for (int k = 0; k < 2; k++) {
            int c4 = lane*2 + k;
            const float* u = (const float*)&W0[k];
            const float* v = (const float*)&W1[k];
            const float* gf = (const float*)&Gg[k];
            const float* bf = (const float*)&Bb[k];
            #pragma unroll
            for (int j = 0; j < 4; j++) {
                float od = a0*u[j] + a1*v[j];
                float nd = (od - mean) * inv * gf[j] + bf[j];
                t[wave][c4*4 + j] = (nd >= 0.f) ? nd : alpha*nd;
            }
        }
        __syncthreads();
        const int c = lane & 31, half = lane >> 5;
        const float* tp = t[wave] + half*256;
        const float* mw = p.mlp_W + half*256*HC + c;
        float partl = 0.f;
        for (int d = 0; d < 256; d++) partl += tp[d] * mw[d*HC];
        partl += __shfl_down(partl, 32);
        // lanes < 32 hold h[c]; three weighted scalar projections
        float v0 = 0.f, v1 = 0.f, v2 = 0.f;
        if (lane < 32) {
            float hc = partl + p.mlp_b[c];
            v0 = hc * p.np_W[c];
            v1 = hc * p.fused[c];
            v2 = hc * p.fused[HC + c];
        }
        #pragma unroll
        for (int off = 16; off > 0; off >>= 1) {
            v0 += __shfl_down(v0, off);
            v1 += __shfl_down(v1, off);
            v2 += __shfl_down(v2, off);
        }
        if (lane == 0) {
            p.out[node] = v0 + p.np_b[0] + p.pb_b[0] + p.pf_b[0];   // base; edges atomically add
            p.sb[node] = v1 + p.fused[64];
            p.sf[node] = v2 + p.fused[65];
        }
        return;
    }
    if (bid < 2 + B_NODE + NN/4) {
        const int node = (bid - 2 - B_NODE) * 4 + wave;
        const unsigned* row = p.vnb + (size_t)node * (DB/4);
        float ss = 0.f;
        #pragma unroll
        for (int k = 0; k < 8; k++) {
            unsigned u = row[lane + 64*k];
            ss += fp8dot4(u, u);
        }
        #pragma unroll
        for (int off = 1; off < 64; off <<= 1) ss += __shfl_xor(ss, off);
        if (lane == 0) p.invb[node] = rsqrtf(ss + 1e-8f);
        return;
    }
    {
        const int node = (bid - 2 - B_NODE - NN/4) * 4 + wave;
        const unsigned* row = p.vnf + (size_t)node * (DF/4);
        unsigned u0 = row[lane], u1 = row[lane + 64];
        float ss = fp8dot4(u0, u0) + fp8dot4(u1, u1);
        #pragma unroll
        for (int off = 1; off < 64; off <<= 1) ss += __shfl_xor(ss, off);
        if (lane == 0) p.invf[node] = rsqrtf(ss + 1e-8f);
    }
}

// ===== K3: CSR fill (src only; dst implied by slot) =====
__global__ __launch_bounds__(256) void fill_kernel(Params p) {
    const int e = blockIdx.x * 256 + threadIdx.x;
    if (e < NE) {
        int s = p.eib[e], d = p.eib[NE + e];
        int pos = atomicAdd(&p.cursor[d], 1);
        p.esrc[pos] = s;
    } else {
        int e2 = e - NE;
        int s = p.eif[e2], d = p.eif[NE + e2];
        int pos = atomicAdd(&p.cursor[NN + d], 1);
        p.esrc[NE + pos] = s;
    }
}

// ===== K4: per-dst edge cosines + scalar scatter (dst row held in regs; deferred reduce) =====
// blocks [0, NN/4)      : body (1 dst node / wave)
// blocks [NN/4, NN/2)   : face
__global__ __launch_bounds__(256) void scat_kernel(Params p) {
    const int wave = threadIdx.x >> 6, lane = threadIdx.x & 63;
    const bool body = blockIdx.x < NN/4;
    const int node = (body ? blockIdx.x : blockIdx.x - NN/4) * 4 + wave;
    const int sbase = body ? 0 : (NN + 1);
    const int s0 = p.starts[sbase + node], s1 = p.starts[sbase + node + 1];
    float acc = 0.f;
    if (body) {
        const int4* D = (const int4*)(p.vnb + (size_t)node * (DB/4));
        int4 d0 = D[lane], d1 = D[lane + 64];
        int i = s0;
        if (i < s1) {
            int s = p.esrc[i];
            const int4* A = (const int4*)(p.vnb + (size_t)s * (DB/4));
            int4 a0 = A[lane], a1 = A[lane + 64];
            float sc = p.invb[s] * p.sb[s];
            int4 b0 = d0, b1 = d1; float sc2 = 0.f;
            while (true) {
                const int i2 = i + 1;
                const bool more = i2 < s1;
                if (more) {                              // prefetch next src row
                    int s2 = p.esrc[i2];
                    const int4* A2 = (const int4*)(p.vnb + (size_t)s2 * (DB/4));
                    b0 = A2[lane]; b1 = A2[lane + 64];
                    sc2 = p.invb[s2] * p.sb[s2];
                }
                acc += (fp8dot16(a0, d0) + fp8dot16(a1, d1)) * sc;
                if (!more) break;
                a0 = b0; a1 = b1; sc = sc2; i = i2;
            }
        }
        #pragma unroll
        for (int off = 1; off < 64; off <<= 1) acc += __shfl_xor(acc, off);
        if (lane == 0) atomicAdd(&p.out[node], acc * p.invb[node]);
    } else {
        const int2* D = (const int2*)(p.vnf + (size_t)node * (DF/4));
        int2 dd = D[lane];
        int i = s0;
        if (i < s1) {
            int s = p.esrc[NE + i];
            const int2* A = (const int2*)(p.vnf + (size_t)s * (DF/4));
            int2 a = A[lane];
            float sc = p.invf[s] * p.sf[s];
            int2 b = dd; float sc2 = 0.f;
            while (true) {
                const int i2 = i + 1;
                const bool more = i2 < s1;
                if (more) {
                    int s2 = p.esrc[NE + i2];
                    const int2* A2 = (const int2*)(p.vnf + (size_t)s2 * (DF/4));
                    b = A2[lane];
                    sc2 = p.invf[s2] * p.sf[s2];
                }
                acc += (fp8dot4((unsigned)a.x, (unsigned)dd.x)
                      + fp8dot4((unsigned)a.y, (unsigned)dd.y)) * sc;
                if (!more) break;
                a = b; sc = sc2; i = i2;
            }
        }
        #pragma unroll
        for (int off = 1; off < 64; off <<= 1) acc += __shfl_xor(acc, off);
        if (lane == 0) atomicAdd(&p.out[node], acc * p.invf[node]);
    }
}

extern "C" void kernel_launch(void* const* d_in, const int* in_sizes, int n_in,
                              void* d_out, int out_size, void* d_ws, size_t ws_size,
                              hipStream_t stream) {
    char* ws = (char*)d_ws;
    size_t off = 0;
    auto alloc = [&](size_t bytes) { void* pp = ws + off; off += (bytes + 15) & ~size_t(15); return pp; };

    Params p;
    p.vb      = (const float*)d_in[1];
    p.vf      = (const float*)d_in[2];
    p.x       = (const float*)d_in[0];
    p.Wq      = (const float*)d_in[3];
    p.Wk      = (const float*)d_in[4];
    p.Wv      = (const float*)d_in[5];
    p.ln_g    = (const float*)d_in[6];
    p.ln_b    = (const float*)d_in[7];
    p.prelu_a = (const float*)d_in[8];
    p.mlp_W   = (const float*)d_in[9];
    p.mlp_b   = (const float*)d_in[10];
    p.np_W    = (const float*)d_in[11];
    p.np_b    = (const float*)d_in[12];
    p.body_W  = (const float*)d_in[13];
    p.body_b  = (const float*)d_in[14];
    p.face_W  = (const float*)d_in[15];
    p.face_b  = (const float*)d_in[16];
    p.pb_W    = (const float*)d_in[17];
    p.pb_b    = (const float*)d_in[18];
    p.pf_W    = (const float*)d_in[19];
    p.pf_b    = (const float*)d_in[20];
    p.eib     = (const int*)d_in[21];
    p.eif     = (const int*)d_in[22];
    p.vnb     = (unsigned*)alloc((size_t)BODY_DW*4);     // 16 MB fp8
    p.vnf     = (unsigned*)alloc((size_t)FACE_DW*4);     //  4 MB fp8
    p.invb    = (float*)alloc((size_t)NN*4);
    p.invf    = (float*)alloc((size_t)NN*4);
    p.a_ws    = (float*)alloc((size_t)NN*2*4);
    p.sb      = (float*)alloc((size_t)NN*4);
    p.sf      = (float*)alloc((size_t)NN*4);
    p.fused   = (float*)alloc((size_t)66*4);
    p.counts  = (int*)alloc((size_t)2*NN*4);
    p.starts  = (int*)alloc((size_t)2*(NN+1)*4);
    p.cursor  = (int*)alloc((size_t)2*NN*4);
    p.esrc    = (int*)alloc((size_t)2*NE*4);
    p.out     = (float*)d_out;

    hipMemsetAsync(p.counts, 0, (size_t)2*NN*4, stream);
    k1_kernel<<<B_BODY + B_FACE + B_CNT + NB + 1, 256, 0, stream>>>(p);
    k2_kernel<<<2 + NN/4 + NN/4 + NN/4, 256, 0, stream>>>(p);
    fill_kernel<<<(2*NE)/256, 256, 0, stream>>>(p);
    scat_kernel<<<NN/2, 256, 0, stream>>>(p);
}

// Round 2
// 222.537 us; speedup vs baseline: 1.1052x; 1.0913x over previous
//
#include <hip/hip_runtime.h>

#define NN 8192     // nodes
#define NB 32       // graphs
#define NG 256      // nodes per graph
#define NE 65536    // edges per graph type
#define DK 512
#define HC 32
#define DB 2048     // body visual dim
#define DF 512      // face visual dim

#define BODY_DW (NN*DB/4)            // 4194304 dwords of fp8x4 (body)
#define FACE_DW (NN*DF/4)            // 1048576 dwords of fp8x4 (face)
#define B_BODY (BODY_DW/2048)        // 2048 pack blocks (8 KB window = 4 body rows)
#define B_FACE (FACE_DW/2048)        // 512 pack blocks (8 KB window = 16 face rows)

typedef float v2f __attribute__((ext_vector_type(2)));

#if __has_builtin(__builtin_amdgcn_cvt_pk_f32_fp8) && __has_builtin(__builtin_amdgcn_cvt_pk_fp8_f32)
#define HW_FP8 1
#else
#define HW_FP8 0
#endif

// ---- fp8 e4m3fn helpers (manual fallback only if builtins missing) ----
__device__ __forceinline__ float fp8_dec(unsigned u) {
    unsigned e = (u >> 3) & 15u, m = u & 7u, s = u & 0x80u;
    float v = e ? __uint_as_float(((e + 120u) << 23) | (m << 20))
                : (float)m * 0.001953125f;
    return s ? -v : v;
}
__device__ __forceinline__ unsigned fp8_enc(float x) {
    unsigned sb = (__float_as_uint(x) >> 24) & 0x80u;
    float a = fabsf(x);
    if (a >= 448.f) return sb | 0x7Eu;
    if (a < 0.015625f) {
        int c = (int)rintf(a * 512.f);
        if (c > 7) return sb | 0x08u;
        return sb | (unsigned)c;
    }
    int ex; (void)frexpf(a, &ex);
    float p = ldexpf(a, 1 - ex);
    int m = (int)rintf((p - 1.f) * 8.f);
    int e = ex - 1 + 7;
    if (m == 8) { m = 0; e++; }
    if (e >= 16) return sb | 0x7Eu;
    return sb | (unsigned)(e << 3) | (unsigned)m;
}
__device__ __forceinline__ unsigned pack4_fp8(float x, float y, float z, float w) {
#if HW_FP8
    int u = __builtin_amdgcn_cvt_pk_fp8_f32(x, y, 0, false);
    u = __builtin_amdgcn_cvt_pk_fp8_f32(z, w, u, true);
    return (unsigned)u;
#else
    return fp8_enc(x) | (fp8_enc(y) << 8) | (fp8_enc(z) << 16) | (fp8_enc(w) << 24);
#endif
}
__device__ __forceinline__ float fp8dot4(unsigned a, unsigned b) {
#if HW_FP8
    v2f al = __builtin_amdgcn_cvt_pk_f32_fp8((int)a, false);
    v2f ah = __builtin_amdgcn_cvt_pk_f32_fp8((int)a, true);
    v2f bl = __builtin_amdgcn_cvt_pk_f32_fp8((int)b, false);
    v2f bh = __builtin_amdgcn_cvt_pk_f32_fp8((int)b, true);
    return al.x*bl.x + al.y*bl.y + ah.x*bh.x + ah.y*bh.y;
#else
    float s = 0.f;
    #pragma unroll
    for (int j = 0; j < 4; j++)
        s += fp8_dec((a >> (8*j)) & 255u) * fp8_dec((b >> (8*j)) & 255u);
    return s;
#endif
}
__device__ __forceinline__ float fp8dot16(int4 a, int4 b) {
    return fp8dot4((unsigned)a.x, (unsigned)b.x) + fp8dot4((unsigned)a.y, (unsigned)b.y)
         + fp8dot4((unsigned)a.z, (unsigned)b.z) + fp8dot4((unsigned)a.w, (unsigned)b.w);
}
__device__ __forceinline__ float d4(float4 v) {
    return v.x*v.x + v.y*v.y + v.z*v.z + v.w*v.w;
}

struct Params {
    const float *vb, *vf, *x, *Wq, *Wk, *Wv, *ln_g, *ln_b, *prelu_a;
    const float *mlp_W, *mlp_b, *np_W, *np_b, *body_W, *body_b, *face_W, *face_b;
    const float *pb_W, *pb_b, *pf_W, *pf_b;
    const int *eib, *eif;
    unsigned *vnb, *vnf;
    float *invb, *invf;
    float *a_ws, *sb, *sf, *fused;   // fused[0..31]=body_W@pb_W, [32..63]=face_W@pf_W, [64]=cb, [65]=cf
    float *out;
};

// ===== K1: fp8 pack + fused fp32 invnorm + rank-2 attention + fused weight vecs =====
// blocks [0, B_BODY)               : body pack + body invnorm (4 rows/block)
// blocks [B_BODY, B_BODY+B_FACE)   : face pack + face invnorm (16 rows/block)
// blocks [+NB)                     : rank-2 attention
// last block                       : bw/fw/cb/cf precompute
__global__ __launch_bounds__(256, 4) void k1_kernel(Params p) {
    __shared__ float2 xs[NG];
    __shared__ float pm[4][4];
    __shared__ float sm4[4];
    __shared__ float rss[16];
    const int bid = blockIdx.x, tid = threadIdx.x;
    const int lane = tid & 63, wave = tid >> 6;

    if (bid < B_BODY + B_FACE) {
        const bool body = bid < B_BODY;
        const float4* __restrict__ src = body ? (const float4*)p.vb : (const float4*)p.vf;
        unsigned* __restrict__ dst = body ? p.vnb : p.vnf;
        const int base = (body ? bid : bid - B_BODY) * 2048 + tid;
        if (tid < 16) rss[tid] = 0.f;
        __syncthreads();
        // 8 independent 16-B loads, all issued before any consumer
        float4 v0 = src[base];
        float4 v1 = src[base + 256];
        float4 v2 = src[base + 512];
        float4 v3 = src[base + 768];
        float4 v4 = src[base + 1024];
        float4 v5 = src[base + 1280];
        float4 v6 = src[base + 1536];
        float4 v7 = src[base + 1792];
        dst[base]        = pack4_fp8(v0.x, v0.y, v0.z, v0.w);
        dst[base + 256]  = pack4_fp8(v1.x, v1.y, v1.z, v1.w);
        dst[base + 512]  = pack4_fp8(v2.x, v2.y, v2.z, v2.w);
        dst[base + 768]  = pack4_fp8(v3.x, v3.y, v3.z, v3.w);
        dst[base + 1024] = pack4_fp8(v4.x, v4.y, v4.z, v4.w);
        dst[base + 1280] = pack4_fp8(v5.x, v5.y, v5.z, v5.w);
        dst[base + 1536] = pack4_fp8(v6.x, v6.y, v6.z, v6.w);
        dst[base + 1792] = pack4_fp8(v7.x, v7.y, v7.z, v7.w);
        if (body) {
            // block window = 4 rows of 512 dwords; j-pairs {2r,2r+1} land in row r for every wave
            float sq[4];
            sq[0] = d4(v0) + d4(v1);
            sq[1] = d4(v2) + d4(v3);
            sq[2] = d4(v4) + d4(v5);
            sq[3] = d4(v6) + d4(v7);
            #pragma unroll
            for (int r = 0; r < 4; r++) {
                float ss = sq[r];
                #pragma unroll
                for (int off = 32; off > 0; off >>= 1) ss += __shfl_xor(ss, off);
                if (lane == 0) atomicAdd(&rss[r], ss);
            }
            __syncthreads();
            if (tid < 4) p.invb[bid*4 + tid] = rsqrtf(rss[tid] + 1e-8f);
        } else {
            // block window = 16 rows of 128 dwords; (wave,j) -> row (wave>>1) + 2j
            float sq[8] = {d4(v0), d4(v1), d4(v2), d4(v3), d4(v4), d4(v5), d4(v6), d4(v7)};
            #pragma unroll
            for (int j = 0; j < 8; j++) {
                float ss = sq[j];
                #pragma unroll
                for (int off = 32; off > 0; off >>= 1) ss += __shfl_xor(ss, off);
                if (lane == 0) atomicAdd(&rss[(wave >> 1) + 2*j], ss);
            }
            __syncthreads();
            if (tid < 16) p.invf[(bid - B_BODY)*16 + tid] = rsqrtf(rss[tid] + 1e-8f);
        }
        return;
    }
    if (bid < B_BODY + B_FACE + NB) {
        const int gg = bid - (B_BODY + B_FACE);
        xs[tid] = ((const float2*)p.x)[gg*NG + tid];
        const int d = tid * 2;
        float q0a = p.Wq[d],    q0b = p.Wq[d+1];
        float q1a = p.Wq[DK+d], q1b = p.Wq[DK+d+1];
        float k0a = p.Wk[d],    k0b = p.Wk[d+1];
        float k1a = p.Wk[DK+d], k1b = p.Wk[DK+d+1];
        float m00 = q0a*k0a + q0b*k0b;
        float m01 = q0a*k1a + q0b*k1b;
        float m10 = q1a*k0a + q1b*k0b;
        float m11 = q1a*k1a + q1b*k1b;
        #pragma unroll
        for (int off = 32; off > 0; off >>= 1) {
            m00 += __shfl_down(m00,off); m01 += __shfl_down(m01,off);
            m10 += __shfl_down(m10,off); m11 += __shfl_down(m11,off);
        }
        if (lane == 0) { pm[wave][0]=m00; pm[wave][1]=m01; pm[wave][2]=m10; pm[wave][3]=m11; }
        __syncthreads();
        if (tid < 4) sm4[tid] = pm[0][tid] + pm[1][tid] + pm[2][tid] + pm[3][tid];
        __syncthreads();
        const float scale = 0.04419417382415922f;  // 1/sqrt(512)
        const float2 xi = xs[tid];
        const float u0 = (xi.x*sm4[0] + xi.y*sm4[2]) * scale;
        const float u1 = (xi.x*sm4[1] + xi.y*sm4[3]) * scale;
        float m = -1e30f;
        for (int j = 0; j < NG; j++) m = fmaxf(m, u0*xs[j].x + u1*xs[j].y);
        float S = 0.f, a0 = 0.f, a1 = 0.f;
        for (int j = 0; j < NG; j++) {
            float2 xj = xs[j];
            float pr = __expf(u0*xj.x + u1*xj.y - m);
            S += pr; a0 += pr*xj.x; a1 += pr*xj.y;
        }
        const float invS = 1.f / S;
        ((float2*)p.a_ws)[gg*NG + tid] = make_float2(a0*invS, a1*invS);
        return;
    }
    // fused projection vectors: bw[cp] = sum_c body_W[cp,c]*pb_W[c]  (and face analog)
    if (tid < HC) {
        float s = 0.f;
        #pragma unroll 8
        for (int c = 0; c < HC; c++) s += p.body_W[tid*HC + c] * p.pb_W[c];
        p.fused[tid] = s;
    } else if (tid < 2*HC) {
        const int cp = tid - HC;
        float s = 0.f;
        #pragma unroll 8
        for (int c = 0; c < HC; c++) s += p.face_W[cp*HC + c] * p.pf_W[c];
        p.fused[HC + cp] = s;
    } else if (tid == 2*HC) {
        float s = 0.f;
        for (int c = 0; c < HC; c++) s += p.body_b[c] * p.pb_W[c];
        p.fused[64] = s;
    } else if (tid == 2*HC + 1) {
        float s = 0.f;
        for (int c = 0; c < HC; c++) s += p.face_b[c] * p.pf_W[c];
        p.fused[65] = s;
    }
}

// ===== K2: node MLP pipeline -> out base + sb/sf scalars (1 node / wave) =====
__global__ __launch_bounds__(256) void k2_kernel(Params p) {
    __shared__ float t[4][DK];
    const int tid = threadIdx.x;
    const int wave = tid >> 6, lane = tid & 63;
    const int node = blockIdx.x * 4 + wave;

    const float a0 = p.a_ws[node*2], a1 = p.a_ws[node*2+1];
    const float4* wv0 = (const float4*)p.Wv;
    const float4* wv1 = (const float4*)(p.Wv + DK);
    const float4* g4 = (const float4*)p.ln_g;
    const float4* b4 = (const float4*)p.ln_b;
    float4 W0[2], W1[2], Gg[2], Bb[2];
    #pragma unroll
    for (int k = 0; k < 2; k++) {
        int c4 = lane*2 + k;
        W0[k] = wv0[c4]; W1[k] = wv1[c4]; Gg[k] = g4[c4]; Bb[k] = b4[c4];
    }
    float s0=0.f, s1=0.f, q00=0.f, q01=0.f, q11=0.f;
    #pragma unroll
    for (int k = 0; k < 2; k++) {
        const float* u = (const float*)&W0[k];
        const float* v = (const float*)&W1[k];
        #pragma unroll
        for (int j = 0; j < 4; j++) {
            s0 += u[j]; s1 += v[j];
            q00 += u[j]*u[j]; q01 += u[j]*v[j]; q11 += v[j]*v[j];
        }
    }
    #pragma unroll
    for (int off = 1; off < 64; off <<= 1) {
        s0 += __shfl_xor(s0,off); s1 += __shfl_xor(s1,off);
        q00 += __shfl_xor(q00,off); q01 += __shfl_xor(q01,off); q11 += __shfl_xor(q11,off);
    }
    const float mean = (a0*s0 + a1*s1) * (1.f/DK);
    const float msq  = (a0*a0*q00 + 2.f*a0*a1*q01 + a1*a1*q11) * (1.f/DK);
    const float inv  = rsqrtf(msq - mean*mean + 1e-5f);
    const float alpha = p.prelu_a[0];
    #pragma unroll
    for (int k = 0; k < 2; k++) {
        int c4 = lane*2 + k;
        const float* u = (const float*)&W0[k];
        const float* v = (const float*)&W1[k];
        const float* gf = (const float*)&Gg[k];
        const float* bf = (const float*)&Bb[k];
        #pragma unroll
        for (int j = 0; j < 4; j++) {
            float od = a0*u[j] + a1*v[j];
            float nd = (od - mean) * inv * gf[j] + bf[j];
            t[wave][c4*4 + j] = (nd >= 0.f) ? nd : alpha*nd;
        }
    }
    __syncthreads();
    const int c = lane & 31, half = lane >> 5;
    const float* tp = t[wave] + half*256;
    const float* mw = p.mlp_W + half*256*HC + c;
    float p0=0.f, p1=0.f, p2=0.f, p3=0.f;
    #pragma unroll 4
    for (int d = 0; d < 256; d += 4) {
        p0 += tp[d]   * mw[d*HC];
        p1 += tp[d+1] * mw[(d+1)*HC];
        p2 += tp[d+2] * mw[(d+2)*HC];
        p3 += tp[d+3] * mw[(d+3)*HC];
    }
    float partl = (p0+p1) + (p2+p3);
    partl += __shfl_down(partl, 32);
    float v0 = 0.f, v1 = 0.f, v2 = 0.f;
    if (lane < 32) {
        float hc = partl + p.mlp_b[c];
        v0 = hc * p.np_W[c];
        v1 = hc * p.fused[c];
        v2 = hc * p.fused[HC + c];
    }
    #pragma unroll
    for (int off = 16; off > 0; off >>= 1) {
        v0 += __shfl_down(v0, off);
        v1 += __shfl_down(v1, off);
        v2 += __shfl_down(v2, off);
    }
    if (lane == 0) {
        p.out[node] = v0 + p.np_b[0] + p.pb_b[0] + p.pf_b[0];   // base; edges atomically add
        p.sb[node] = v1 + p.fused[64];
        p.sf[node] = v2 + p.fused[65];
    }
}

// ===== K3: edge-direct cosine scatter (no CSR) =====
// blocks [0, NE/8)         : body, 2 edges/wave
// blocks [NE/8, +NE/16)    : face, 4 edges/wave
__global__ __launch_bounds__(256) void scat_kernel(Params p) {
    const int wave = threadIdx.x >> 6, lane = threadIdx.x & 63;
    if (blockIdx.x < NE/8) {
        const int e = blockIdx.x * 8 + wave * 2;
        const int sA = p.eib[e],     dA = p.eib[NE + e];
        const int sB = p.eib[e + 1], dB = p.eib[NE + e + 1];
        const int4* ap0 = (const int4*)(p.vnb + (size_t)sA * (DB/4));
        const int4* bp0 = (const int4*)(p.vnb + (size_t)dA * (DB/4));
        const int4* ap1 = (const int4*)(p.vnb + (size_t)sB * (DB/4));
        const int4* bp1 = (const int4*)(p.vnb + (size_t)dB * (DB/4));
        int4 a00 = ap0[lane], a01 = ap0[lane + 64];
        int4 b00 = bp0[lane], b01 = bp0[lane + 64];
        int4 a10 = ap1[lane], a11 = ap1[lane + 64];
        int4 b10 = bp1[lane], b11 = bp1[lane + 64];
        float x0 = fp8dot16(a00, b00) + fp8dot16(a01, b01);
        float x1 = fp8dot16(a10, b10) + fp8dot16(a11, b11);
        #pragma unroll
        for (int off = 32; off > 0; off >>= 1) {
            x0 += __shfl_xor(x0, off);
            x1 += __shfl_xor(x1, off);
        }
        if (lane == 0) {
            atomicAdd(&p.out[dA], x0 * p.invb[sA] * p.invb[dA] * p.sb[sA]);
            atomicAdd(&p.out[dB], x1 * p.invb[sB] * p.invb[dB] * p.sb[sB]);
        }
    } else {
        const int e = (blockIdx.x - NE/8) * 16 + wave * 4;
        const int s0 = p.eif[e],     d0 = p.eif[NE + e];
        const int s1 = p.eif[e + 1], d1 = p.eif[NE + e + 1];
        const int s2 = p.eif[e + 2], d2 = p.eif[NE + e + 2];
        const int s3 = p.eif[e + 3], d3 = p.eif[NE + e + 3];
        const int2* ap0 = (const int2*)(p.vnf + (size_t)s0 * (DF/4));
        const int2* bp0 = (const int2*)(p.vnf + (size_t)d0 * (DF/4));
        const int2* ap1 = (const int2*)(p.vnf + (size_t)s1 * (DF/4));
        const int2* bp1 = (const int2*)(p.vnf + (size_t)d1 * (DF/4));
        const int2* ap2 = (const int2*)(p.vnf + (size_t)s2 * (DF/4));
        const int2* bp2 = (const int2*)(p.vnf + (size_t)d2 * (DF/4));
        const int2* ap3 = (const int2*)(p.vnf + (size_t)s3 * (DF/4));
        const int2* bp3 = (const int2*)(p.vnf + (size_t)d3 * (DF/4));
        int2 a0 = ap0[lane], b0 = bp0[lane];
        int2 a1 = ap1[lane], b1 = bp1[lane];
        int2 a2 = ap2[lane], b2 = bp2[lane];
        int2 a3 = ap3[lane], b3 = bp3[lane];
        float x0 = fp8dot4((unsigned)a0.x,(unsigned)b0.x) + fp8dot4((unsigned)a0.y,(unsigned)b0.y);
        float x1 = fp8dot4((unsigned)a1.x,(unsigned)b1.x) + fp8dot4((unsigned)a1.y,(unsigned)b1.y);
        float x2 = fp8dot4((unsigned)a2.x,(unsigned)b2.x) + fp8dot4((unsigned)a2.y,(unsigned)b2.y);
        float x3 = fp8dot4((unsigned)a3.x,(unsigned)b3.x) + fp8dot4((unsigned)a3.y,(unsigned)b3.y);
        #pragma unroll
        for (int off = 32; off > 0; off >>= 1) {
            x0 += __shfl_xor(x0, off);
            x1 += __shfl_xor(x1, off);
            x2 += __shfl_xor(x2, off);
            x3 += __shfl_xor(x3, off);
        }
        if (lane == 0) {
            atomicAdd(&p.out[d0], x0 * p.invf[s0] * p.invf[d0] * p.sf[s0]);
            atomicAdd(&p.out[d1], x1 * p.invf[s1] * p.invf[d1] * p.sf[s1]);
            atomicAdd(&p.out[d2], x2 * p.invf[s2] * p.invf[d2] * p.sf[s2]);
            atomicAdd(&p.out[d3], x3 * p.invf[s3] * p.invf[d3] * p.sf[s3]);
        }
    }
}

extern "C" void kernel_launch(void* const* d_in, const int* in_sizes, int n_in,
                              void* d_out, int out_size, void* d_ws, size_t ws_size,
                              hipStream_t stream) {
    char* ws = (char*)d_ws;
    size_t off = 0;
    auto alloc = [&](size_t bytes) { void* pp = ws + off; off += (bytes + 15) & ~size_t(15); return pp; };

    Params p;
    p.vb      = (const float*)d_in[1];
    p.vf      = (const float*)d_in[2];
    p.x       = (const float*)d_in[0];
    p.Wq      = (const float*)d_in[3];
    p.Wk      = (const float*)d_in[4];
    p.Wv      = (const float*)d_in[5];
    p.ln_g    = (const float*)d_in[6];
    p.ln_b    = (const float*)d_in[7];
    p.prelu_a = (const float*)d_in[8];
    p.mlp_W   = (const float*)d_in[9];
    p.mlp_b   = (const float*)d_in[10];
    p.np_W    = (const float*)d_in[11];
    p.np_b    = (const float*)d_in[12];
    p.body_W  = (const float*)d_in[13];
    p.body_b  = (const float*)d_in[14];
    p.face_W  = (const float*)d_in[15];
    p.face_b  = (const float*)d_in[16];
    p.pb_W    = (const float*)d_in[17];
    p.pb_b    = (const float*)d_in[18];
    p.pf_W    = (const float*)d_in[19];
    p.pf_b    = (const float*)d_in[20];
    p.eib     = (const int*)d_in[21];
    p.eif     = (const int*)d_in[22];
    p.vnb     = (unsigned*)alloc((size_t)BODY_DW*4);     // 16 MB fp8
    p.vnf     = (unsigned*)alloc((size_t)FACE_DW*4);     //  4 MB fp8
    p.invb    = (float*)alloc((size_t)NN*4);
    p.invf    = (float*)alloc((size_t)NN*4);
    p.a_ws    = (float*)alloc((size_t)NN*2*4);
    p.sb      = (float*)alloc((size_t)NN*4);
    p.sf      = (float*)alloc((size_t)NN*4);
    p.fused   = (float*)alloc((size_t)66*4);
    p.out     = (float*)d_out;

    k1_kernel<<<B_BODY + B_FACE + NB + 1, 256, 0, stream>>>(p);
    k2_kernel<<<NN/4, 256, 0, stream>>>(p);
    scat_kernel<<<NE/8 + NE/16, 256, 0, stream>>>(p);
}